// Round 3
// baseline (349.874 us; speedup 1.0000x reference)
//
#include <hip/hip_runtime.h>

// DilatedConv1D: out[b,o,p] = bias[o] + sum_c x[b,c,p]*W[o,c,0] + x[b,c,p+2]*W[o,c,1]
// x: (8,128,32768) fp32, W: (128,128,2) fp32, bias: (128) fp32, out: (8,128,32769) fp32.
// Strategy: bf16 MFMA GEMM, M=128 (OUT), N=positions, two K=128 passes (taps share X tile).
// Fragments use short8 (guide-verified builtin signature on gfx950); bf16 conversion is
// manual round-to-nearest-even bit math.

namespace {

constexpr int kB   = 8;
constexpr int kC   = 128;
constexpr int kT   = 32768;
constexpr int kP   = kT + 1;                    // 32769 output positions
constexpr int kOut = 128;
constexpr int kNP  = 64;                        // positions per block tile
constexpr int kNTiles = (kP + kNP - 1) / kNP;   // 513
constexpr int kLStride = 136;                   // shorts per pos-row: 128 + 8 pad (272 B, 16B-aligned)

typedef __attribute__((ext_vector_type(8))) short short8;
typedef __attribute__((ext_vector_type(4))) float f32x4;

// float -> bf16 bits, round-to-nearest-even (inputs are finite gaussians; NaN not handled)
__device__ inline short f2bf(float f) {
    unsigned int u = __builtin_bit_cast(unsigned int, f);
    u += 0x7fffu + ((u >> 16) & 1u);
    return (short)(u >> 16);
}

__global__ __launch_bounds__(256, 2) void dconv_mfma(
    const float* __restrict__ x, const float* __restrict__ W,
    const float* __restrict__ bias, float* __restrict__ out)
{
    // X tile in LDS, transposed: xs[pos][c] (bf16 bits), pos in [0, 66) (64 outputs + 2 halo)
    __shared__ __align__(16) short xs[66 * kLStride];

    const int tid  = threadIdx.x;
    const int lane = tid & 63;
    const int wv   = tid >> 6;                  // wave 0..3 -> rows [32*wv, 32*wv+32)
    const int bb   = blockIdx.x / kNTiles;
    const int tile = blockIdx.x % kNTiles;
    const int p0   = tile * kNP;

    // ---------------- stage X tile: xs[pos][c] = bf16(x[bb][c][p0+pos]) ----------------
    // thread t handles pos = t&63 (plus halo for t&63 < 2), c-range = (t>>6)*32 .. +32.
    // Global dword loads coalesced across lanes (consecutive pos); LDS writes b128.
    {
        const float* xb = x + (size_t)bb * kC * kT;
        const int cg = tid >> 6;
        const int nrep = ((tid & 63) < 2) ? 2 : 1;
        for (int rep = 0; rep < nrep; ++rep) {
            const int pos = (tid & 63) + rep * 64;   // 0..63, then halo 64/65
            const int gp  = p0 + pos;
            const bool ok = gp < kT;                 // positions >= T are the zero pad
            const float* col = xb + gp;
            #pragma unroll
            for (int i = 0; i < 4; ++i) {
                const int c0 = cg * 32 + i * 8;
                short8 v;
                #pragma unroll
                for (int j = 0; j < 8; ++j) {
                    const float f = ok ? col[(size_t)(c0 + j) * kT] : 0.0f;
                    v[j] = f2bf(f);
                }
                *reinterpret_cast<short8*>(xs + pos * kLStride + c0) = v;
            }
        }
    }

    // ---------------- W fragments in registers (A-operand layout) ----------------
    // A[m][k]: m = lane&15 (o within 16-row chunk), k = (lane>>4)*8 + j (c within 32-k step).
    // Raw W is [o][c][tap] -> 16 consecutive floats cover 8 c's x 2 taps; split in-register.
    const int rowbase = wv * 32;
    short8 wf[2][2][4];                         // [tap][rowchunk][kstep]
    #pragma unroll
    for (int cc = 0; cc < 2; ++cc) {
        const int o = rowbase + cc * 16 + (lane & 15);
        #pragma unroll
        for (int s = 0; s < 4; ++s) {
            const int cb = s * 32 + (lane >> 4) * 8;
            const float4* wp = reinterpret_cast<const float4*>(W + o * (kC * 2) + cb * 2);
            short8 f0, f1;
            #pragma unroll
            for (int q = 0; q < 4; ++q) {
                const float4 v = wp[q];
                f0[q * 2 + 0] = f2bf(v.x);  f1[q * 2 + 0] = f2bf(v.y);
                f0[q * 2 + 1] = f2bf(v.z);  f1[q * 2 + 1] = f2bf(v.w);
            }
            wf[0][cc][s] = f0;
            wf[1][cc][s] = f1;
        }
    }

    // ---------------- accumulators initialized with bias ----------------
    // D layout: col = lane&15, row = (lane>>4)*4 + r
    f32x4 acc[2][4];                            // [rowchunk][colchunk]
    #pragma unroll
    for (int cc = 0; cc < 2; ++cc) {
        const int ob = rowbase + cc * 16 + (lane >> 4) * 4;
        f32x4 a;
        a[0] = bias[ob + 0]; a[1] = bias[ob + 1];
        a[2] = bias[ob + 2]; a[3] = bias[ob + 3];
        #pragma unroll
        for (int nc = 0; nc < 4; ++nc) acc[cc][nc] = a;
    }

    __syncthreads();

    // ---------------- MFMA main loop: 2 taps x 4 k-steps x 4 col-chunks ----------------
    #pragma unroll
    for (int tap = 0; tap < 2; ++tap) {
        #pragma unroll
        for (int s = 0; s < 4; ++s) {
            const int cb = s * 32 + (lane >> 4) * 8;
            #pragma unroll
            for (int nc = 0; nc < 4; ++nc) {
                // B[k][n]: n = lane&15 (position in 16-col chunk), k = (lane>>4)*8 + j (c)
                const int pos = nc * 16 + (lane & 15) + 2 * tap;
                const short8 bf = *reinterpret_cast<const short8*>(xs + pos * kLStride + cb);
                acc[0][nc] = __builtin_amdgcn_mfma_f32_16x16x32_bf16(wf[tap][0][s], bf, acc[0][nc], 0, 0, 0);
                acc[1][nc] = __builtin_amdgcn_mfma_f32_16x16x32_bf16(wf[tap][1][s], bf, acc[1][nc], 0, 0, 0);
            }
        }
    }

    // ---------------- store ----------------
    float* ob = out + (size_t)bb * kOut * kP;
    #pragma unroll
    for (int nc = 0; nc < 4; ++nc) {
        const int col = p0 + nc * 16 + (lane & 15);
        if (col < kP) {
            #pragma unroll
            for (int cc = 0; cc < 2; ++cc) {
                const int orow = rowbase + cc * 16 + (lane >> 4) * 4;
                #pragma unroll
                for (int r = 0; r < 4; ++r) {
                    ob[(size_t)(orow + r) * kP + col] = acc[cc][nc][r];
                }
            }
        }
    }
}

}  // namespace

extern "C" void kernel_launch(void* const* d_in, const int* in_sizes, int n_in,
                              void* d_out, int out_size, void* d_ws, size_t ws_size,
                              hipStream_t stream) {
    const float* x    = (const float*)d_in[0];
    const float* W    = (const float*)d_in[1];
    const float* bias = (const float*)d_in[2];
    float* out        = (float*)d_out;

    dim3 grid(kB * kNTiles);   // 8 * 513 = 4104 blocks
    dim3 block(256);
    hipLaunchKernelGGL(dconv_mfma, grid, block, 0, stream, x, W, bias, out);
}

// Round 4
// 281.632 us; speedup vs baseline: 1.2423x; 1.2423x over previous
//
#include <hip/hip_runtime.h>

// DilatedConv1D: out[b,o,p] = bias[o] + sum_c x[b,c,p]*W[o,c,0] + x[b,c,p+2]*W[o,c,1]
// x: (8,128,32768) fp32, W: (128,128,2) fp32, bias: (128) fp32, out: (8,128,32769) fp32.
// bf16 MFMA GEMM. Round-4 changes: 128-pos tiles, staged loads with explicit
// load-all/convert-all split for memory-level parallelism, guard-free fast path.

namespace {

constexpr int kB   = 8;
constexpr int kC   = 128;
constexpr int kT   = 32768;
constexpr int kP   = kT + 1;                    // 32769 output positions
constexpr int kOut = 128;
constexpr int kNP  = 128;                       // positions per block tile
constexpr int kNTiles = (kP + kNP - 1) / kNP;   // 257
constexpr int kLStride = 136;                   // shorts per pos-row (272 B, 16B-aligned)

typedef __attribute__((ext_vector_type(8))) short short8;
typedef __attribute__((ext_vector_type(4))) float f32x4;

// float -> bf16 bits, round-to-nearest-even (finite inputs)
__device__ __forceinline__ short f2bf(float f) {
    unsigned int u = __builtin_bit_cast(unsigned int, f);
    u += 0x7fffu + ((u >> 16) & 1u);
    return (short)(u >> 16);
}

// Stage xs[pos][c] = bf16(x[bb][c][p0+pos]) for pos in [0,130).
// Loads are hoisted into a register array before any convert/LDS write so the
// compiler keeps 8 coalesced 256B loads in flight per wave.
template <bool GUARD>
__device__ __forceinline__ void stage_tile(const float* __restrict__ xb,
                                           short* __restrict__ xs,
                                           int tid, int p0) {
    {
        const int pos = tid & 127;
        const int gp  = p0 + pos;
        const bool ok = !GUARD || (gp < kT);     // pos >= T reads the zero pad
        const float* col = xb + (ok ? gp : 0);
        const int c0base = (tid >> 7) * 64;
        #pragma unroll
        for (int ch = 0; ch < 8; ++ch) {
            const int c0 = c0base + ch * 8;
            float r[8];
            #pragma unroll
            for (int j = 0; j < 8; ++j) r[j] = col[(c0 + j) << 15];  // c stride = kT
            short8 v;
            #pragma unroll
            for (int j = 0; j < 8; ++j) v[j] = ok ? f2bf(r[j]) : (short)0;
            *reinterpret_cast<short8*>(xs + pos * kLStride + c0) = v;
        }
    }
    // halo rows 128,129: 32 lanes cover 2 pos x 128 c
    if (tid < 32) {
        const int pos = 128 + (tid & 1);
        const int gp  = p0 + pos;
        const bool ok = !GUARD || (gp < kT);
        const float* col = xb + (ok ? gp : 0);
        const int c0 = (tid >> 1) * 8;
        float r[8];
        #pragma unroll
        for (int j = 0; j < 8; ++j) r[j] = col[(c0 + j) << 15];
        short8 v;
        #pragma unroll
        for (int j = 0; j < 8; ++j) v[j] = ok ? f2bf(r[j]) : (short)0;
        *reinterpret_cast<short8*>(xs + pos * kLStride + c0) = v;
    }
}

__global__ __launch_bounds__(256, 2) void dconv_mfma(
    const float* __restrict__ x, const float* __restrict__ W,
    const float* __restrict__ bias, float* __restrict__ out)
{
    __shared__ __align__(16) short xs[130 * kLStride];   // 35.4 KB

    const int tid  = threadIdx.x;
    const int lane = tid & 63;
    const int wv   = tid >> 6;                  // wave -> output rows [32*wv, 32*wv+32)
    const int bb   = blockIdx.x / kNTiles;
    const int tile = blockIdx.x % kNTiles;
    const int p0   = tile * kNP;

    // ---------------- W fragments (A-operand layout), issued before staging ----------
    // A[m][k]: m = lane&15 (o), k = (lane>>4)*8 + j (c). Raw W[o][c][tap]:
    // float4 covers 2 c x 2 taps; split taps in-register.
    const int rowbase = wv * 32;
    short8 wf[2][2][4];                         // [tap][rowchunk][kstep]
    #pragma unroll
    for (int cc = 0; cc < 2; ++cc) {
        const int o = rowbase + cc * 16 + (lane & 15);
        #pragma unroll
        for (int s = 0; s < 4; ++s) {
            const int cb = s * 32 + (lane >> 4) * 8;
            const float4* wp = reinterpret_cast<const float4*>(W + o * (kC * 2) + cb * 2);
            float4 wr[4];
            #pragma unroll
            for (int q = 0; q < 4; ++q) wr[q] = wp[q];
            short8 f0, f1;
            #pragma unroll
            for (int q = 0; q < 4; ++q) {
                f0[q * 2 + 0] = f2bf(wr[q].x);  f1[q * 2 + 0] = f2bf(wr[q].y);
                f0[q * 2 + 1] = f2bf(wr[q].z);  f1[q * 2 + 1] = f2bf(wr[q].w);
            }
            wf[0][cc][s] = f0;
            wf[1][cc][s] = f1;
        }
    }

    // ---------------- stage X tile ----------------
    const float* xb = x + (size_t)bb * kC * kT;
    if (p0 + 129 < kT) stage_tile<false>(xb, xs, tid, p0);
    else               stage_tile<true>(xb, xs, tid, p0);

    // ---------------- accumulators initialized with bias ----------------
    // D layout: col = lane&15, row = (lane>>4)*4 + r
    f32x4 acc[2][8];                            // [rowchunk][colchunk]
    #pragma unroll
    for (int cc = 0; cc < 2; ++cc) {
        const int ob = rowbase + cc * 16 + (lane >> 4) * 4;
        f32x4 a;
        a[0] = bias[ob + 0]; a[1] = bias[ob + 1];
        a[2] = bias[ob + 2]; a[3] = bias[ob + 3];
        #pragma unroll
        for (int nc = 0; nc < 8; ++nc) acc[cc][nc] = a;
    }

    __syncthreads();

    // ---------------- MFMA main loop: 2 taps x 4 k-steps x 8 col-chunks x 2 rowchunks --
    #pragma unroll
    for (int tap = 0; tap < 2; ++tap) {
        #pragma unroll
        for (int s = 0; s < 4; ++s) {
            const int cb = s * 32 + (lane >> 4) * 8;
            #pragma unroll
            for (int nc = 0; nc < 8; ++nc) {
                // B[k][n]: n = lane&15 (pos), k = (lane>>4)*8 + j (c)
                const int pos = nc * 16 + (lane & 15) + 2 * tap;
                const short8 bf = *reinterpret_cast<const short8*>(xs + pos * kLStride + cb);
                acc[0][nc] = __builtin_amdgcn_mfma_f32_16x16x32_bf16(wf[tap][0][s], bf, acc[0][nc], 0, 0, 0);
                acc[1][nc] = __builtin_amdgcn_mfma_f32_16x16x32_bf16(wf[tap][1][s], bf, acc[1][nc], 0, 0, 0);
            }
        }
    }

    // ---------------- store ----------------
    float* ob = out + (size_t)bb * kOut * kP;
    #pragma unroll
    for (int nc = 0; nc < 8; ++nc) {
        const int col = p0 + nc * 16 + (lane & 15);
        if (col < kP) {
            #pragma unroll
            for (int cc = 0; cc < 2; ++cc) {
                const int orow = rowbase + cc * 16 + (lane >> 4) * 4;
                #pragma unroll
                for (int r = 0; r < 4; ++r) {
                    ob[(size_t)(orow + r) * kP + col] = acc[cc][nc][r];
                }
            }
        }
    }
}

}  // namespace

extern "C" void kernel_launch(void* const* d_in, const int* in_sizes, int n_in,
                              void* d_out, int out_size, void* d_ws, size_t ws_size,
                              hipStream_t stream) {
    const float* x    = (const float*)d_in[0];
    const float* W    = (const float*)d_in[1];
    const float* bias = (const float*)d_in[2];
    float* out        = (float*)d_out;

    dim3 grid(kB * kNTiles);   // 8 * 257 = 2056 blocks
    dim3 block(256);
    hipLaunchKernelGGL(dconv_mfma, grid, block, 0, stream, x, W, bias, out);
}